// Round 2
// baseline (510.412 us; speedup 1.0000x reference)
//
#include <hip/hip_runtime.h>
#include <hip/hip_bf16.h>

// MultisenseLearner: out[b] = logsumexp_{s,t}( sum_d W[j,d,s]*V[i,d,t] + wb[j,s] + vb[i,t] )
// V,W: (50000, 300, 4); vb,wb: (50000,4); IJ: (100000,2); out: (100000,)
//
// Dtypes are ambiguous at the ABI (in_sizes are element counts), so we detect
// them on-device each call (graph-capture safe, data-deterministic):
//   flags[0] = 1 if float tensors are f32 (else bf16)
//   flags[1] = 1 if IJ is int64 (else int32)
// One wave64 per batch element; 16B/lane coalesced gathers; f32 accumulation;
// 6-step butterfly reduce; lane 0 does bias + exp/log epilogue.

constexpr int D  = 300;
constexpr int NS = 4;

typedef unsigned short ushort8 __attribute__((ext_vector_type(8)));

__device__ __forceinline__ float b2f(unsigned short u) {
    return __uint_as_float(((unsigned int)u) << 16);
}

__global__ void detect_kernel(const unsigned int* __restrict__ Vw,
                              const unsigned int* __restrict__ IJw,
                              int* __restrict__ flags)
{
    const int lane = threadIdx.x & 63;
    // f32-vs-bf16: low halfwords of f32 words are random mantissa bits -> as
    // bf16, exponent field >= 126 (|x| >= 0.5) about half the time. True bf16
    // Xavier data (|x| <= 0.1405) has exponent field <= 124 always.
    unsigned int w0 = Vw[2 * lane];
    unsigned int w1 = Vw[2 * lane + 1];
    unsigned int e0 = (w0 >> 7) & 0xFFu;   // exp field of low halfword as bf16
    unsigned int e1 = (w1 >> 7) & 0xFFu;
    bool big = (e0 >= 126u) || (e1 >= 126u);
    // int64-vs-int32: indices < 2^31, so int64 data has all odd words zero.
    bool odd_nonzero = (lane < 32) ? (IJw[2 * lane + 1] != 0u) : false;
    int isF32 = __any(big) ? 1 : 0;
    int isI64 = __any(odd_nonzero) ? 0 : 1;
    if (threadIdx.x == 0) {
        flags[0] = isF32;
        flags[1] = isI64;
    }
}

__global__ __launch_bounds__(256) void multisense_kernel(
    const void* __restrict__ V_,
    const void* __restrict__ W_,
    const void* __restrict__ vb_,
    const void* __restrict__ wb_,
    const int*  __restrict__ IJ32,
    void*       __restrict__ out_,
    int B,
    const int*  __restrict__ flags)
{
    const int lane = threadIdx.x & 63;
    const int b    = blockIdx.x * (blockDim.x >> 6) + (threadIdx.x >> 6);
    if (b >= B) return;

    const int isF32 = flags[0];
    const int isI64 = flags[1];

    int i, j;
    if (isI64) { i = IJ32[4 * b]; j = IJ32[4 * b + 2]; }   // low words of int64 pair
    else       { i = IJ32[2 * b]; j = IJ32[2 * b + 1]; }

    float acc[NS][NS];
#pragma unroll
    for (int s = 0; s < NS; ++s)
#pragma unroll
        for (int t = 0; t < NS; ++t)
            acc[s][t] = 0.0f;

    if (isF32) {
        const float* Vr = (const float*)V_ + (size_t)i * (D * NS);
        const float* Wr = (const float*)W_ + (size_t)j * (D * NS);
        // lane l handles d = l + 64k, k=0..4 (k=4: lanes 0..43). 16B/lane loads.
#pragma unroll
        for (int k = 0; k < 5; ++k) {
            const int d = lane + 64 * k;
            if (d < D) {
                const float4 v4 = *reinterpret_cast<const float4*>(Vr + d * NS);
                const float4 w4 = *reinterpret_cast<const float4*>(Wr + d * NS);
                const float v[NS] = {v4.x, v4.y, v4.z, v4.w};
                const float w[NS] = {w4.x, w4.y, w4.z, w4.w};
#pragma unroll
                for (int s = 0; s < NS; ++s)
#pragma unroll
                    for (int t = 0; t < NS; ++t)
                        acc[s][t] = fmaf(w[s], v[t], acc[s][t]);
            }
        }
    } else {
        const unsigned short* Vr = (const unsigned short*)V_ + (size_t)i * (D * NS);
        const unsigned short* Wr = (const unsigned short*)W_ + (size_t)j * (D * NS);
        // lane l handles d-pair (2l+128k, 2l+128k+1), k=0..2 (k=2: lanes 0..21).
#pragma unroll
        for (int k = 0; k < 3; ++k) {
            const int d = 2 * lane + 128 * k;
            if (d < D) {
                const ushort8 v8 = *reinterpret_cast<const ushort8*>(Vr + d * NS);
                const ushort8 w8 = *reinterpret_cast<const ushort8*>(Wr + d * NS);
                float v[8], w[8];
#pragma unroll
                for (int e = 0; e < 8; ++e) {
                    v[e] = b2f(v8[e]);
                    w[e] = b2f(w8[e]);
                }
#pragma unroll
                for (int s = 0; s < NS; ++s)
#pragma unroll
                    for (int t = 0; t < NS; ++t) {
                        acc[s][t] = fmaf(w[s],     v[t],     acc[s][t]);
                        acc[s][t] = fmaf(w[4 + s], v[4 + t], acc[s][t]);
                    }
            }
        }
    }

    // Butterfly reduction across the 64-lane wave (16 values x 6 steps).
#pragma unroll
    for (int off = 32; off; off >>= 1)
#pragma unroll
        for (int s = 0; s < NS; ++s)
#pragma unroll
            for (int t = 0; t < NS; ++t)
                acc[s][t] += __shfl_xor(acc[s][t], off, 64);

    if (lane == 0) {
        float wbj[NS], vbi[NS];
        if (isF32) {
            const float* vbp = (const float*)vb_;
            const float* wbp = (const float*)wb_;
#pragma unroll
            for (int s = 0; s < NS; ++s) {
                wbj[s] = wbp[(size_t)j * NS + s];
                vbi[s] = vbp[(size_t)i * NS + s];
            }
        } else {
            const unsigned short* vbp = (const unsigned short*)vb_;
            const unsigned short* wbp = (const unsigned short*)wb_;
#pragma unroll
            for (int s = 0; s < NS; ++s) {
                wbj[s] = b2f(wbp[(size_t)j * NS + s]);
                vbi[s] = b2f(vbp[(size_t)i * NS + s]);
            }
        }
        float sum = 0.0f;
#pragma unroll
        for (int s = 0; s < NS; ++s)
#pragma unroll
            for (int t = 0; t < NS; ++t)
                sum += expf(acc[s][t] + wbj[s] + vbi[t]);
        const float res = logf(sum);
        if (isF32) ((float*)out_)[b] = res;
        else       ((__hip_bfloat16*)out_)[b] = __float2bfloat16(res);
    }
}

extern "C" void kernel_launch(void* const* d_in, const int* in_sizes, int n_in,
                              void* d_out, int out_size, void* d_ws, size_t ws_size,
                              hipStream_t stream) {
    const void* V  = d_in[0];
    const void* W  = d_in[1];
    const void* vb = d_in[2];
    const void* wb = d_in[3];
    const int*  IJ = (const int*)d_in[4];
    int* flags = (int*)d_ws;

    const int B = out_size;                 // one output per batch element
    hipLaunchKernelGGL(detect_kernel, dim3(1), dim3(64), 0, stream,
                       (const unsigned int*)V, (const unsigned int*)IJ, flags);

    const int wavesPerBlock = 4;            // 256 threads
    dim3 block(256);
    dim3 grid((B + wavesPerBlock - 1) / wavesPerBlock);
    hipLaunchKernelGGL(multisense_kernel, grid, block, 0, stream,
                       V, W, vb, wb, IJ, d_out, B, flags);
}

// Round 3
// 507.262 us; speedup vs baseline: 1.0062x; 1.0062x over previous
//
#include <hip/hip_runtime.h>
#include <hip/hip_bf16.h>

// MultisenseLearner: out[b] = logsumexp_{s,t}( sum_d W[j,d,s]*V[i,d,t] + wb[j,s] + vb[i,t] )
// V,W: (50000,300,4) f32; vb,wb: (50000,4) f32; IJ: (100000,2) int; out: (100000,) f32.
// (f32 proven in R2: FETCH_SIZE==484MB==unique f32 footprint; bf16 interpretation NaN'd in R1.)
//
// One wave64 per batch element. Key change vs R2: all 10 row-gather float4 loads
// + 2 bias loads issue BEFORE any FMA (R2 had VGPR=36 -> serialized loads ->
// latency-bound at 2.5 TB/s). Value-splitting butterfly reduction (72 ops vs 192)
// lands (s,t) on lane bits[5:2]; one exp per lane; 4-step exp reduce.

constexpr int D   = 300;
constexpr int NS  = 4;
constexpr int ROW = D * NS;   // 1200 floats per gathered row

__global__ __launch_bounds__(256) void multisense_kernel(
    const float* __restrict__ V,
    const float* __restrict__ W,
    const float* __restrict__ vb,
    const float* __restrict__ wb,
    const unsigned int* __restrict__ IJw,   // raw 32-bit view of IJ
    float* __restrict__ out,
    int B)
{
    const int lane = threadIdx.x & 63;
    const int b    = blockIdx.x * (blockDim.x >> 6) + (threadIdx.x >> 6);
    if (b >= B) return;   // whole wave uniform (B % 4waves == 0 anyway)

    // --- int64-vs-int32 detection (per wave, data-deterministic) ---
    // Indices < 50000 < 2^31, so int64 data has every odd 32-bit word == 0.
    // P(int32 data aliasing) ~ (2e-5)^32 ~ 0.
    unsigned int probe = (lane < 32) ? IJw[2 * lane + 1] : 0u;
    const bool isI64 = (__ballot(probe != 0u) == 0ull);

    int i, j;
    if (isI64) { i = (int)IJw[4 * (size_t)b];     j = (int)IJw[4 * (size_t)b + 2]; }
    else       { i = (int)IJw[2 * (size_t)b];     j = (int)IJw[2 * (size_t)b + 1]; }

    const float* __restrict__ Vr = V + (size_t)i * ROW;
    const float* __restrict__ Wr = W + (size_t)j * ROW;

    // Epilogue ownership: after the splitting reduction, lane holds the full
    // d-sum for sense pair m = (lane>>2)&15, i.e. s=(lane>>4)&3, t=(lane>>2)&3.
    const int s_idx = (lane >> 4) & 3;
    const int t_idx = (lane >> 2) & 3;

    // --- issue ALL loads up front: 10x float4 gathers + 2 bias scalars ---
    const float wbj = wb[(size_t)j * NS + s_idx];
    const float vbi = vb[(size_t)i * NS + t_idx];

    float4 va[5], wa[5];
#pragma unroll
    for (int k = 0; k < 4; ++k) {
        const int d = lane + 64 * k;
        va[k] = *reinterpret_cast<const float4*>(Vr + (size_t)d * NS);
        wa[k] = *reinterpret_cast<const float4*>(Wr + (size_t)d * NS);
    }
    // tail: d = 256+lane, valid for lanes 0..43 (D=300). Clamp address (stay
    // in-row, avoids OOB on last vocab row), zero W side to kill contribution.
    {
        const int  d4 = 256 + lane;
        const int  dc = (d4 < D) ? d4 : 0;
        const float m = (d4 < D) ? 1.0f : 0.0f;
        va[4] = *reinterpret_cast<const float4*>(Vr + (size_t)dc * NS);
        wa[4] = *reinterpret_cast<const float4*>(Wr + (size_t)dc * NS);
        wa[4].x *= m; wa[4].y *= m; wa[4].z *= m; wa[4].w *= m;
    }

    // --- 4x4 Gram accumulation, f32 ---
    float acc[16];
#pragma unroll
    for (int m = 0; m < 16; ++m) acc[m] = 0.0f;
#pragma unroll
    for (int k = 0; k < 5; ++k) {
        const float v0 = va[k].x, v1 = va[k].y, v2 = va[k].z, v3 = va[k].w;
        const float w0 = wa[k].x, w1 = wa[k].y, w2 = wa[k].z, w3 = wa[k].w;
        acc[ 0] = fmaf(w0, v0, acc[ 0]); acc[ 1] = fmaf(w0, v1, acc[ 1]);
        acc[ 2] = fmaf(w0, v2, acc[ 2]); acc[ 3] = fmaf(w0, v3, acc[ 3]);
        acc[ 4] = fmaf(w1, v0, acc[ 4]); acc[ 5] = fmaf(w1, v1, acc[ 5]);
        acc[ 6] = fmaf(w1, v2, acc[ 6]); acc[ 7] = fmaf(w1, v3, acc[ 7]);
        acc[ 8] = fmaf(w2, v0, acc[ 8]); acc[ 9] = fmaf(w2, v1, acc[ 9]);
        acc[10] = fmaf(w2, v2, acc[10]); acc[11] = fmaf(w2, v3, acc[11]);
        acc[12] = fmaf(w3, v0, acc[12]); acc[13] = fmaf(w3, v1, acc[13]);
        acc[14] = fmaf(w3, v2, acc[14]); acc[15] = fmaf(w3, v3, acc[15]);
    }

    // --- value-splitting wave reduction: 16 vals -> 1 val/lane in 4 steps ---
    const bool b5 = (lane & 32) != 0;
    float r8[8];
#pragma unroll
    for (int m = 0; m < 8; ++m) {
        const float send = b5 ? acc[m]     : acc[m + 8];
        const float keep = b5 ? acc[m + 8] : acc[m];
        r8[m] = keep + __shfl_xor(send, 32, 64);
    }
    const bool b4 = (lane & 16) != 0;
    float r4[4];
#pragma unroll
    for (int m = 0; m < 4; ++m) {
        const float send = b4 ? r8[m]     : r8[m + 4];
        const float keep = b4 ? r8[m + 4] : r8[m];
        r4[m] = keep + __shfl_xor(send, 16, 64);
    }
    const bool b3 = (lane & 8) != 0;
    float r2[2];
#pragma unroll
    for (int m = 0; m < 2; ++m) {
        const float send = b3 ? r4[m]     : r4[m + 2];
        const float keep = b3 ? r4[m + 2] : r4[m];
        r2[m] = keep + __shfl_xor(send, 8, 64);
    }
    const bool b2 = (lane & 4) != 0;
    float r1;
    {
        const float send = b2 ? r2[0] : r2[1];
        const float keep = b2 ? r2[1] : r2[0];
        r1 = keep + __shfl_xor(send, 4, 64);
    }
    // finish the d-sum across lane bits 1:0 (same sense-pair class)
    r1 += __shfl_xor(r1, 2, 64);
    r1 += __shfl_xor(r1, 1, 64);

    // --- epilogue: one exp per lane, reduce 16 distinct classes ---
    float e = expf(r1 + wbj + vbi);
    e += __shfl_xor(e,  4, 64);
    e += __shfl_xor(e,  8, 64);
    e += __shfl_xor(e, 16, 64);
    e += __shfl_xor(e, 32, 64);   // every lane now holds sum of the 16 exps

    if (lane == 0) out[b] = logf(e);
}

extern "C" void kernel_launch(void* const* d_in, const int* in_sizes, int n_in,
                              void* d_out, int out_size, void* d_ws, size_t ws_size,
                              hipStream_t stream) {
    const float* V  = (const float*)d_in[0];
    const float* W  = (const float*)d_in[1];
    const float* vb = (const float*)d_in[2];
    const float* wb = (const float*)d_in[3];
    const unsigned int* IJ = (const unsigned int*)d_in[4];
    float* out = (float*)d_out;

    const int B = out_size;                  // one output per batch element
    const int wavesPerBlock = 4;             // 256 threads
    dim3 block(256);
    dim3 grid((B + wavesPerBlock - 1) / wavesPerBlock);
    hipLaunchKernelGGL(multisense_kernel, grid, block, 0, stream,
                       V, W, vb, wb, IJ, out, B);
}